// Round 11
// baseline (81.056 us; speedup 1.0000x reference)
//
#include <hip/hip_runtime.h>

#define NB 32
#define TT 512
#define UU 100
#define UM 101   // U+1
#define VV 4096
#define NEG (-1e30f)
#define PW 16            // consumer ring depth (diagonals)
#define WINB 32          // diagonals per window
#define NWIN 20          // windows w=0..19 cover d = 1..640 >= dend_max+1
#define GSTRIDE 5        // producer blocks per n (each builds 4 windows in order)
#define DST 720          // stream d-stride per n (reads bounded by dend+47 <= 658)
#define L2E 1.4426950408889634f
#define LN2 0.6931471805599453f

__device__ __forceinline__ float vexp2(float x){ float r; asm("v_exp_f32 %0, %1" : "=v"(r) : "v"(x)); return r; }
__device__ __forceinline__ float vlog2(float x){ float r; asm("v_log_f32 %0, %1" : "=v"(r) : "v"(x)); return r; }

// logaddexp in log2 domain
__device__ __forceinline__ float lae2(float a, float b) {
    float m  = fmaxf(a, b);
    float nd = fminf(a, b) - m;          // = -|a-b|
    return m + vlog2(1.0f + vexp2(nd));
}

__global__ void clear_k(int* __restrict__ flags) {
    flags[threadIdx.x] = 0;              // NB*NWIN = 640
}

// blocks 0..31: DP consumer for n = bid.
// blocks 32..191: producer (n, g) = divmod(bid-32, GSTRIDE); builds windows
//   w = g, g+GSTRIDE, ... IN ORDER (staggered completion so the consumer is
//   fed early windows first), flagging each window when done.
__global__ __launch_bounds__(256, 1) void fused_k(
        const float* __restrict__ enc, const float* __restrict__ dec,
        const int* __restrict__ tgt, const int* __restrict__ ilen,
        const int* __restrict__ tlen,
        float* __restrict__ st, int* __restrict__ flags, float* __restrict__ out) {
    int bid = blockIdx.x;
    int tid = threadIdx.x;

    if (bid >= NB) {
        // ---------------- producer ----------------
        int pb = bid - NB;
        int n = pb / GSTRIDE, g = pb % GSTRIDE;
        __shared__ int   tgtL[UU];
        __shared__ float dvxL[UU];
        if (tid < UU) {
            int y = tgt[n * UU + tid];
            tgtL[tid] = y;
            dvxL[tid] = dec[((size_t)n * UM + tid) * VV + y] * L2E;
        }
        int tin = ilen[n], tg = tlen[n];
        __syncthreads();
        const float* encn = enc + (size_t)n * TT * VV;
        int* flg = flags + n * NWIN;

        for (int w = g; w < NWIN; w += GSTRIDE) {
            if (w * WINB + 1 > tin + tg) break;   // later windows never needed
            float ev[16];
            // phase 1: issue all gather loads, no uses (16 misses in flight/lane)
#pragma unroll
            for (int it = 0; it < 16; ++it) {
                int idx = tid + it * 256;            // 0..4095
                int dm = idx >> 7, u = idx & 127;
                int d = w * WINB + 1 + dm;
                int t = d - u;
                bool ok = (u >= 1) & (u <= tg) & (t >= 0) & (t < tin);
                ev[it] = NEG;
                if (ok) ev[it] = encn[(size_t)t * VV + tgtL[u - 1]];   // exec-masked
            }
            // phase 2: select + coalesced store
#pragma unroll
            for (int it = 0; it < 16; ++it) {
                int idx = tid + it * 256;
                int dm = idx >> 7, u = idx & 127;
                int d = w * WINB + 1 + dm;
                int t = d - u;
                bool ok = (u >= 1) & (u <= tg) & (t >= 0) & (t < tin);
                int uc = max(u, 1);
                float e = ok ? fmaf(ev[it], L2E, dvxL[uc - 1]) : NEG;
                st[((size_t)n * DST + d) * 128 + u] = e;
            }
            __syncthreads();                  // all stores drained to L2 (vmcnt 0)
            if (tid == 0) {
                __threadfence();              // release: writeback to coherence point
                atomicExch(&flg[w], 1);       // device-scope flag
            }
            __syncthreads();
        }
        return;
    }

    // ---------------- consumer (one wave per n) ----------------
    int n = bid;
    __shared__ float blkL[864];   // blkL[128+t] = enc[n][t][0]*L2E, NEG pads
    const float* encn = enc + (size_t)n * TT * VV;
    for (int i = tid; i < 864; i += 256)
        blkL[i] = (i >= 128 && i < 128 + TT) ? encn[(size_t)(i - 128) * VV] * L2E : NEG;
    __syncthreads();
    if (tid >= 64) return;
    int lane = tid;

    int tin = ilen[n], tg = tlen[n];
    int dend = tin - 1 + tg;
    int wlast = (dend - 1) >> 5;                 // window containing dend
    const float* decn = dec + (size_t)n * UM * VV;
    float bd0 = decn[(size_t)min(2 * lane, UM - 1) * VV] * L2E;
    float bd1 = decn[(size_t)min(2 * lane + 1, UM - 1) * VV] * L2E;
    const float* sp = st + (size_t)n * DST * 128 + 2 * lane;
    int ib0 = 127 - 2 * lane;     // blkL idx of slot0's blk[t-1] is ib0 + d
    bool cap0 = (2 * lane == tg), cap1 = (2 * lane + 1 == tg);
    bool fx16 = (lane == 16), fx32 = (lane == 32), fx48 = (lane == 48);
    float a0 = (lane == 0) ? 0.0f : NEG;         // alpha[0][0] = 0 at d=0
    float a1 = NEG;
    float res = NEG;
    int* flg = flags + n * NWIN;
    int wseen = -1;

    float Ae0[PW], Ae1[PW], Ab0[PW], Ab1[PW];
    float Be0[PW], Be1[PW], Bb0[PW], Bb1[PW];

    // wait until windows 0..w are all flagged (monotone; lane0 spins, wave follows)
    auto WAITW = [&](int w) {
        w = min(w, wlast);
        while (wseen < w) {
            ++wseen;
            if (lane == 0) {
                while (__hip_atomic_load(&flg[wseen], __ATOMIC_ACQUIRE,
                                         __HIP_MEMORY_SCOPE_AGENT) == 0) {}
            }
        }
    };

    auto REFILL = [&](float (&Re0)[PW], float (&Re1)[PW],
                      float (&Rb0)[PW], float (&Rb1)[PW], int d0) {
        WAITW((d0 + PW - 2) >> 5);               // window of diagonal d0+PW-1
#pragma unroll
        for (int k = 0; k < PW; ++k) {
            int d = d0 + k;
            // device-scope relaxed atomic load: L3-coherent (fresh cross-XCD data),
            // no fences -> prefetch rings never drain.
            unsigned long long raw = __hip_atomic_load(
                (const unsigned long long*)(sp + (size_t)d * 128),
                __ATOMIC_RELAXED, __HIP_MEMORY_SCOPE_AGENT);
            union { unsigned long long q; float2 f; } cv; cv.q = raw;
            Re0[k] = cv.f.x; Re1[k] = cv.f.y;
            Rb0[k] = blkL[ib0 + d] + bd0;
            Rb1[k] = blkL[ib0 + d - 1] + bd1;
        }
        __builtin_amdgcn_sched_barrier(0);
    };

    auto STEPS = [&](float (&Re0)[PW], float (&Re1)[PW],
                     float (&Rb0)[PW], float (&Rb1)[PW], int d0) {
#pragma unroll
        for (int k = 0; k < PW; ++k) {
            int dd = d0 + k;
            // left neighbor of u=2L is lane L-1's a1: DPP row_shr:1 + seam fixups
            int sh = __builtin_amdgcn_update_dpp(__float_as_int(NEG), __float_as_int(a1),
                                                 0x111, 0xF, 0xF, false);   // row_shr:1
            float s15 = __int_as_float(__builtin_amdgcn_readlane(__float_as_int(a1), 15));
            float s31 = __int_as_float(__builtin_amdgcn_readlane(__float_as_int(a1), 31));
            float s47 = __int_as_float(__builtin_amdgcn_readlane(__float_as_int(a1), 47));
            float l0 = __int_as_float(sh);
            l0 = fx16 ? s15 : l0;
            l0 = fx32 ? s31 : l0;
            l0 = fx48 ? s47 : l0;
            float bt0 = a0 + Rb0[k], et0 = l0 + Re0[k];
            float bt1 = a1 + Rb1[k], et1 = a0 + Re1[k];   // old a0: same-lane left neighbor
            a0 = lae2(bt0, et0);
            a1 = lae2(bt1, et1);
            if (dd == dend) { if (cap0) res = a0; if (cap1) res = a1; }
        }
        __builtin_amdgcn_sched_barrier(0);
    };

    REFILL(Ae0, Ae1, Ab0, Ab1, 1);
    for (int d0 = 1; d0 <= dend; d0 += 2 * PW) {
        REFILL(Be0, Be1, Bb0, Bb1, d0 + PW);     STEPS(Ae0, Ae1, Ab0, Ab1, d0);
        REFILL(Ae0, Ae1, Ab0, Ab1, d0 + 2 * PW); STEPS(Be0, Be1, Bb0, Bb1, d0 + PW);
        // reads past dend (<= dend+47 <= 658 < DST) hit built-NEG or junk; res is
        // latched exactly at dd == dend before junk can flow in -> capture-safe.
    }

    if (cap0 | cap1) {
        float fin  = blkL[128 + tin - 1];
        float bdtg = decn[(size_t)tg * VV] * L2E;
        out[n] = (res + fin + bdtg) * LN2;
    }
}

extern "C" void kernel_launch(void* const* d_in, const int* in_sizes, int n_in,
                              void* d_out, int out_size, void* d_ws, size_t ws_size,
                              hipStream_t hs) {
    const float* enc  = (const float*)d_in[0];
    const float* dec  = (const float*)d_in[1];
    const int*   tgt  = (const int*)d_in[2];
    const int*   ilen = (const int*)d_in[3];
    const int*   tlen = (const int*)d_in[4];
    float* out = (float*)d_out;

    float* st    = (float*)d_ws;                          // NB*DST*128 floats = 11.8 MB
    int*   flags = (int*)(st + (size_t)NB * DST * 128);   // NB*NWIN = 640 ints

    hipLaunchKernelGGL(clear_k, dim3(1), dim3(NB * NWIN), 0, hs, flags);
    hipLaunchKernelGGL(fused_k, dim3(NB + NB * GSTRIDE), dim3(256), 0, hs,
                       enc, dec, tgt, ilen, tlen, st, flags, out);
}

// Round 12
// 78.039 us; speedup vs baseline: 1.0387x; 1.0387x over previous
//
#include <hip/hip_runtime.h>

#define NB 32
#define TT 512
#define UU 100
#define UM 101   // U+1
#define VV 4096
#define NEG (-1e30f)
#define WIN 64
#define L2E 1.4426950408889634f
#define LN2 0.6931471805599453f

__device__ __forceinline__ float vexp2(float x){ float r; asm("v_exp_f32 %0, %1" : "=v"(r) : "v"(x)); return r; }
__device__ __forceinline__ float vlog2(float x){ float r; asm("v_log_f32 %0, %1" : "=v"(r) : "v"(x)); return r; }

// logaddexp in log2 domain
__device__ __forceinline__ float lae2(float a, float b) {
    float m  = fmaxf(a, b);
    float nd = fminf(a, b) - m;          // = -|a-b|
    return m + vlog2(1.0f + vexp2(nd));
}

// k0: per-n bitonic sort of (y, j) pairs by y ascending; pads get INT_MAX.
__global__ __launch_bounds__(128) void sort_k(const int* __restrict__ tgt,
                                              int* __restrict__ sy,
                                              int* __restrict__ su) {
    __shared__ int ky[128], pu[128];
    int n = blockIdx.x, tid = threadIdx.x;
    ky[tid] = (tid < UU) ? tgt[n * UU + tid] : 0x7FFFFFFF;
    pu[tid] = tid;
    __syncthreads();
    for (int k = 2; k <= 128; k <<= 1)
        for (int j = k >> 1; j > 0; j >>= 1) {
            int i = tid, ix = i ^ j;
            if (ix > i) {
                bool up = ((i & k) == 0);
                int a = ky[i], b = ky[ix];
                if ((a > b) == up) {
                    ky[i] = b; ky[ix] = a;
                    int tmp = pu[i]; pu[i] = pu[ix]; pu[ix] = tmp;
                }
            }
            __syncthreads();
        }
    sy[n * 128 + tid] = ky[tid];
    su[n * 128 + tid] = pu[tid];
}

// k1: DRAM-row-burst gather. Block (tt, n) covers enc rows t = tt*32 .. +31.
// One wave = one row t; lanes = ascending sorted y -> 64 ascending addresses
// within one 16KB row (row-hit bursts). LDS transpose -> coalesced stores of
// em[n][j][t] (row-major in t), values pre-scaled by L2E, NEG where invalid.
__global__ __launch_bounds__(256) void gather_k(
        const float* __restrict__ enc, const int* __restrict__ ilen,
        const int* __restrict__ tlen, const int* __restrict__ sy,
        const int* __restrict__ su, float* __restrict__ em) {
    int tt = blockIdx.x, n = blockIdx.y;
    int tin = ilen[n], tg = tlen[n];
    int t0 = tt * 32;
    if (t0 >= tin) return;
    __shared__ float tile[32][104];      // [t_local][j], padded
    __shared__ int syL[128], suL[128];
    int tid = threadIdx.x;
    if (tid < 128) { syL[tid] = sy[n * 128 + tid]; suL[tid] = su[n * 128 + tid]; }
    __syncthreads();
    const float* encn = enc + (size_t)n * TT * VV;
    int wave = tid >> 6, lane = tid & 63;

    float v[16];
    // phase 1: issue all loads (independent, exec-masked); per instr the wave's
    // addresses are ascending within one enc row.
#pragma unroll
    for (int it = 0; it < 8; ++it) {
        int t = t0 + wave * 8 + it;
        bool tok = (t < tin);
        int s1 = lane + 64;
        int j0 = suL[lane];
        int j1 = (s1 < 128) ? suL[s1] : 0;
        v[2 * it]     = NEG;
        v[2 * it + 1] = NEG;
        if (tok && j0 < tg)              v[2 * it]     = encn[(size_t)t * VV + syL[lane]] * L2E;
        if (tok && s1 < 100 && j1 < tg)  v[2 * it + 1] = encn[(size_t)t * VV + syL[s1]] * L2E;
    }
    // phase 2: LDS transpose scatter
#pragma unroll
    for (int it = 0; it < 8; ++it) {
        int tl = wave * 8 + it;
        int s1 = lane + 64;
        tile[tl][suL[lane]] = v[2 * it];
        if (s1 < 100) tile[tl][suL[s1]] = v[2 * it + 1];
    }
    __syncthreads();
    // coalesced store: em[n][j][t0 + tl]
    for (int idx = tid; idx < UU * 32; idx += 256) {
        int j = idx >> 5, tl = idx & 31;
        em[((size_t)n * UU + j) * TT + t0 + tl] = tile[tl][j];
    }
}

// k2: fused DP (R6-proven consumer). Wave 0 consumes 64-diagonal LDS windows;
// waves 1..15 stage the next window from em with cheap coalesced reads.
// Lane L owns u=2L (a0) and u=2L+1 (a1).
__global__ __launch_bounds__(1024, 1) void dp_k(
        const float* __restrict__ enc, const float* __restrict__ dec,
        const int* __restrict__ tgt, const int* __restrict__ ilen,
        const int* __restrict__ tlen, const float* __restrict__ em,
        float* __restrict__ out) {
    __shared__ float emL[2][WIN][130];   // [buf][dm][u], padded (+2)
    __shared__ float blkL[864];          // blkL[128+t] = enc[n][t][0]*L2E, NEG pads
    __shared__ float dvxL[UU];           // dec[n][j][y_j]*L2E

    int n = blockIdx.x, tid = threadIdx.x;
    int tin = ilen[n], tg = tlen[n];
    int dend = tin - 1 + tg;
    int E = (dend + WIN - 1) / WIN;
    const float* encn = enc + (size_t)n * TT * VV;
    const float* decn = dec + (size_t)n * UM * VV;

    for (int i = tid; i < 864; i += 1024)
        blkL[i] = (i >= 128 && i < 128 + TT) ? encn[(size_t)(i - 128) * VV] * L2E : NEG;
    if (tid < UU) {
        int y = tgt[n * UU + tid];
        dvxL[tid] = decn[(size_t)tid * VV + y] * L2E;
    }
    __syncthreads();

    int wave = tid >> 6, lane = tid & 63;
    const float* emn = em + (size_t)n * UU * TT;

    // producers: stage window w (diagonals base+1 .. base+64).
    // row r: 0..99 -> data column u=r+1; r=100 -> u=0 (NEG); r=101..127 -> u=r (NEG).
    auto FILLWIN = [&](int w, int base) {
        for (int r = wave - 1; r < 128; r += 15) {
            int u = (r < 100) ? (r + 1) : ((r == 100) ? 0 : r);
            int t = base + 1 + lane - u;          // dm = lane
            float val = NEG;
            if (r < 100 && r < tg && t >= 0 && t < tin)
                val = emn[(size_t)r * TT + t] + dvxL[r];
            emL[w][lane][u] = val;
        }
    };

    if (wave != 0) FILLWIN(0, 0);        // prefill window 0

    // consumer state
    bool fx16 = (lane == 16), fx32 = (lane == 32), fx48 = (lane == 48);
    bool cap0 = (2 * lane == tg), cap1 = (2 * lane + 1 == tg);
    float bd0 = decn[(size_t)min(2 * lane, UM - 1) * VV] * L2E;
    float bd1 = decn[(size_t)min(2 * lane + 1, UM - 1) * VV] * L2E;
    int ib0 = 127 - 2 * lane;            // blkL idx of slot0's blk[t-1] is ib0 + d
    float a0 = (lane == 0) ? 0.0f : NEG; // alpha[0][0] = 0 at d=0
    float a1 = NEG;
    float res = NEG;

    float Re0[8], Re1[8], Rb0[8], Rb1[8], Se0[8], Se1[8], Sb0[8], Sb1[8];

    auto REFILL = [&](float (&e0)[8], float (&e1)[8], float (&b0)[8], float (&b1)[8],
                      const float* emb, int j0, int base) {
#pragma unroll
        for (int k = 0; k < 8; ++k) {
            int dm = j0 + k, d = base + 1 + dm;
            float2 ev = *(const float2*)(emb + dm * 130 + 2 * lane);
            e0[k] = ev.x; e1[k] = ev.y;
            b0[k] = blkL[ib0 + d] + bd0;
            b1[k] = blkL[ib0 + d - 1] + bd1;
        }
        __builtin_amdgcn_sched_barrier(0);
    };

    auto STEPS = [&](float (&e0)[8], float (&e1)[8], float (&b0)[8], float (&b1)[8],
                     int j0, int base) {
#pragma unroll
        for (int k = 0; k < 8; ++k) {
            int dd = base + 1 + j0 + k;
            // left neighbor of u=2L is lane L-1's a1: DPP row_shr:1 + seam fixups
            int sh = __builtin_amdgcn_update_dpp(__float_as_int(NEG), __float_as_int(a1),
                                                 0x111, 0xF, 0xF, false);   // row_shr:1
            float s15 = __int_as_float(__builtin_amdgcn_readlane(__float_as_int(a1), 15));
            float s31 = __int_as_float(__builtin_amdgcn_readlane(__float_as_int(a1), 31));
            float s47 = __int_as_float(__builtin_amdgcn_readlane(__float_as_int(a1), 47));
            float l0 = __int_as_float(sh);
            l0 = fx16 ? s15 : l0;
            l0 = fx32 ? s31 : l0;
            l0 = fx48 ? s47 : l0;
            float bt0 = a0 + b0[k], et0 = l0 + e0[k];
            float bt1 = a1 + b1[k], et1 = a0 + e1[k];   // old a0: same-lane left neighbor
            a0 = lae2(bt0, et0);
            a1 = lae2(bt1, et1);
            if (dd == dend) { if (cap0) res = a0; if (cap1) res = a1; }
        }
        __builtin_amdgcn_sched_barrier(0);
    };

    __syncthreads();                     // window 0 ready

    for (int e = 0; e < E; ++e) {
        if (wave == 0) {
            int base = e * WIN;
            const float* emb = &emL[e & 1][0][0];
            REFILL(Re0, Re1, Rb0, Rb1, emb, 0, base);
            REFILL(Se0, Se1, Sb0, Sb1, emb, 8, base);  STEPS(Re0, Re1, Rb0, Rb1, 0, base);
            REFILL(Re0, Re1, Rb0, Rb1, emb, 16, base); STEPS(Se0, Se1, Sb0, Sb1, 8, base);
            REFILL(Se0, Se1, Sb0, Sb1, emb, 24, base); STEPS(Re0, Re1, Rb0, Rb1, 16, base);
            REFILL(Re0, Re1, Rb0, Rb1, emb, 32, base); STEPS(Se0, Se1, Sb0, Sb1, 24, base);
            REFILL(Se0, Se1, Sb0, Sb1, emb, 40, base); STEPS(Re0, Re1, Rb0, Rb1, 32, base);
            REFILL(Re0, Re1, Rb0, Rb1, emb, 48, base); STEPS(Se0, Se1, Sb0, Sb1, 40, base);
            REFILL(Se0, Se1, Sb0, Sb1, emb, 56, base); STEPS(Re0, Re1, Rb0, Rb1, 48, base);
            STEPS(Se0, Se1, Sb0, Sb1, 56, base);
        } else if (e + 1 < E) {
            FILLWIN((e + 1) & 1, (e + 1) * WIN);
        }
        __syncthreads();
    }

    if (wave == 0 && (cap0 | cap1)) {
        float fin  = blkL[128 + tin - 1];
        float bdtg = decn[(size_t)tg * VV] * L2E;
        out[n] = (res + fin + bdtg) * LN2;
    }
}

extern "C" void kernel_launch(void* const* d_in, const int* in_sizes, int n_in,
                              void* d_out, int out_size, void* d_ws, size_t ws_size,
                              hipStream_t hs) {
    const float* enc  = (const float*)d_in[0];
    const float* dec  = (const float*)d_in[1];
    const int*   tgt  = (const int*)d_in[2];
    const int*   ilen = (const int*)d_in[3];
    const int*   tlen = (const int*)d_in[4];
    float* out = (float*)d_out;

    float* em = (float*)d_ws;                         // NB*UU*TT floats = 6.55 MB
    int*   sy = (int*)(em + (size_t)NB * UU * TT);    // NB*128 ints
    int*   su = sy + NB * 128;                        // NB*128 ints

    hipLaunchKernelGGL(sort_k,   dim3(NB), dim3(128), 0, hs, tgt, sy, su);
    hipLaunchKernelGGL(gather_k, dim3(16, NB), dim3(256), 0, hs,
                       enc, ilen, tlen, sy, su, em);
    hipLaunchKernelGGL(dp_k,     dim3(NB), dim3(1024), 0, hs,
                       enc, dec, tgt, ilen, tlen, em, out);
}